// Round 1
// baseline (219.336 us; speedup 1.0000x reference)
//
#include <hip/hip_runtime.h>
#include <stdint.h>

typedef short bf16x8 __attribute__((ext_vector_type(8)));
typedef float f32x16 __attribute__((ext_vector_type(16)));

#define LOG2E 1.44269504088896340736f
#define LN2f  0.69314718055994530942f

constexpr int Bn = 512;
constexpr int Ln = 2048;
constexpr int Cn = 32;
constexpr int NSEG = 16;
constexpr int SEGLEN = 128;   // Ln / NSEG
constexpr int WARM = 16;
constexpr int NGRP = 16;      // Bn / 32

// pack two f32 -> one VGPR of two bf16 (round-half-away via +0x8000, then take high halves)
__device__ __forceinline__ uint32_t pack2_bf16(float lo, float hi) {
    uint32_t a = __float_as_uint(lo) + 0x8000u;
    uint32_t b = __float_as_uint(hi) + 0x8000u;
    // v_perm: sel bytes 0-3 pick from src1 (=a), 4-7 from src0 (=b)
    return __builtin_amdgcn_perm(b, a, 0x07060302u);
}

// One wave (64 thr) per block. blockIdx -> (group g of 32 batches, segment s).
// Lane layout: n = batch = lane&31 (D col / B col), h = lane>>5.
// D reg r holds state row m = (r&3) + 8*(r>>2) + 4*h for batch n.
// MFMA1 covers K-block {states 4h + (j&3) + 8*(j>>2)}, MFMA2 same +16  ==> D regs 0..7 / 8..15
// pack directly into next step's B1/B2 with NO cross-lane movement.
__global__ __launch_bounds__(64, 1) void crf_scan(
    const float* __restrict__ emis, const float* __restrict__ trans,
    const int* __restrict__ tags, const int* __restrict__ mask,
    float* __restrict__ dDelta, float* __restrict__ dScore, int* __restrict__ dMsum)
{
    __shared__ float Tlds[Cn * Cn];
    const int lane = threadIdx.x;
    const int h    = lane >> 5;
    const int bl   = lane & 31;
    const int g    = blockIdx.x & (NGRP - 1);
    const int s    = blockIdx.x >> 4;
    const int b    = g * 32 + bl;
    const size_t eb = (size_t)b * Ln * Cn;   // emission row base (elements)
    const size_t tB = (size_t)b * Ln;        // tags/mask row base

    for (int i = lane; i < Cn * Cn; i += 64) Tlds[i] = trans[i];

    // Constant A fragments: A[m=bl][k'], k' = 8h + j; col(j) = 4h + (j&3) + 8*(j>>2) (+16 for A2)
    bf16x8 A1, A2;
    {
        float e1[8], e2[8];
        #pragma unroll
        for (int j = 0; j < 8; ++j) {
            int c1 = 4 * h + (j & 3) + 8 * (j >> 2);
            e1[j] = __expf(trans[bl * Cn + c1]);
            e2[j] = __expf(trans[bl * Cn + c1 + 16]);
        }
        union { uint32_t u[4]; bf16x8 v; } ua, ub;
        #pragma unroll
        for (int q = 0; q < 4; ++q) {
            ua.u[q] = pack2_bf16(e1[2*q], e1[2*q+1]);
            ub.u[q] = pack2_bf16(e2[2*q], e2[2*q+1]);
        }
        A1 = ua.v; A2 = ub.v;
    }

    const f32x16 zeroC = {0.f,0.f,0.f,0.f,0.f,0.f,0.f,0.f,0.f,0.f,0.f,0.f,0.f,0.f,0.f,0.f};

    f32x16 Dv;                 // current p (f32, post emission-multiply)
    bf16x8 B1, B2;             // packed p for next MFMA
    float offF = 0.f;          // accumulated log scale (natural log)
    float adj  = 0.f;          // pending log2 rescale, folded into next step's exp
    float score = 0.f;
    int   msum = 0;
    int   prevTag = 0;
    float4 buf[8][4];          // 8-step emission prefetch pipeline (128 VGPRs)
    int tcur[8], mcur[8];

    const int t0 = (s == 0) ? 0 : s * SEGLEN - WARM;

    auto loadEm = [&](int t, float4 (&dst)[4]) {
        const float4* p = (const float4*)(emis + eb + (size_t)t * Cn + 4 * h);
        dst[0] = p[0]; dst[1] = p[2]; dst[2] = p[4]; dst[3] = p[6];
    };

    auto packB = [&]() {
        union { uint32_t u[4]; bf16x8 v; } p1, p2;
        #pragma unroll
        for (int q = 0; q < 4; ++q) {
            p1.u[q] = pack2_bf16(Dv[2*q],     Dv[2*q + 1]);
            p2.u[q] = pack2_bf16(Dv[8 + 2*q], Dv[8 + 2*q + 1]);
        }
        B1 = p1.v; B2 = p2.v;
    };

    auto initStep = [&](const float4 (&bu)[4]) {   // p := exp(e_t)
        #pragma unroll
        for (int q = 0; q < 4; ++q) {
            Dv[4*q+0] = __expf(bu[q].x);
            Dv[4*q+1] = __expf(bu[q].y);
            Dv[4*q+2] = __expf(bu[q].z);
            Dv[4*q+3] = __expf(bu[q].w);
        }
        packB();
    };

    auto stepMfma = [&](const float4 (&bu)[4], float a) {   // p := (E p) * exp(e)*2^a
        f32x16 acc = __builtin_amdgcn_mfma_f32_32x32x16_bf16(A1, B1, zeroC, 0, 0, 0);
        acc = __builtin_amdgcn_mfma_f32_32x32x16_bf16(A2, B2, acc, 0, 0, 0);
        #pragma unroll
        for (int q = 0; q < 4; ++q) {
            float x0 = exp2f(fmaf(bu[q].x, LOG2E, a));
            float x1 = exp2f(fmaf(bu[q].y, LOG2E, a));
            float x2 = exp2f(fmaf(bu[q].z, LOG2E, a));
            float x3 = exp2f(fmaf(bu[q].w, LOG2E, a));
            Dv[4*q+0] = acc[4*q+0] * x0;
            Dv[4*q+1] = acc[4*q+1] * x1;
            Dv[4*q+2] = acc[4*q+2] * x2;
            Dv[4*q+3] = acc[4*q+3] * x3;
        }
        packB();
    };

    auto renorm = [&]() {   // exact power-of-2 renorm; scale folded into next exp via adj
        float m0 = fmaxf(fmaxf(Dv[0], Dv[1]),  fmaxf(Dv[2],  Dv[3]));
        float m1 = fmaxf(fmaxf(Dv[4], Dv[5]),  fmaxf(Dv[6],  Dv[7]));
        float m2 = fmaxf(fmaxf(Dv[8], Dv[9]),  fmaxf(Dv[10], Dv[11]));
        float m3 = fmaxf(fmaxf(Dv[12],Dv[13]), fmaxf(Dv[14], Dv[15]));
        float m  = fmaxf(fmaxf(m0, m1), fmaxf(m2, m3));
        m = fmaxf(m, __shfl_xor(m, 32, 64));
        int k = (int)((__float_as_uint(m) >> 23) & 0xffu) - 126;
        offF += (float)k * LN2f;
        adj = -(float)k;
    };

    auto sumD = [&]() {
        float t = 0.f;
        #pragma unroll
        for (int r = 0; r < 16; ++r) t += Dv[r];
        t += __shfl_xor(t, 32, 64);
        return t;
    };

    auto loadTagsMask = [&](int t) {
        int4 a0 = *(const int4*)(tags + tB + t);
        int4 a1 = *(const int4*)(tags + tB + t + 4);
        int4 c0 = *(const int4*)(mask + tB + t);
        int4 c1 = *(const int4*)(mask + tB + t + 4);
        tcur[0]=a0.x; tcur[1]=a0.y; tcur[2]=a0.z; tcur[3]=a0.w;
        tcur[4]=a1.x; tcur[5]=a1.y; tcur[6]=a1.z; tcur[7]=a1.w;
        mcur[0]=c0.x; mcur[1]=c0.y; mcur[2]=c0.z; mcur[3]=c0.w;
        mcur[4]=c1.x; mcur[5]=c1.y; mcur[6]=c1.z; mcur[7]=c1.w;
    };

    auto realBlock = [&](int tb) {
        int tn = min(tb + 8, Ln - 8);                 // next-block tag/mask prefetch (clamped)
        int4 a0 = *(const int4*)(tags + tB + tn);
        int4 a1 = *(const int4*)(tags + tB + tn + 4);
        int4 c0 = *(const int4*)(mask + tB + tn);
        int4 c1 = *(const int4*)(mask + tB + tn + 4);
        float gv[8];
        #pragma unroll
        for (int u = 0; u < 8; ++u)
            gv[u] = emis[eb + (size_t)(tb + u) * Cn + tcur[u]];
        #pragma unroll
        for (int u = 0; u < 8; ++u) {
            stepMfma(buf[u], (u == 0) ? adj : 0.f);
            loadEm(min(tb + u + 8, Ln - 1), buf[u]);
            float fm = (float)mcur[u];
            msum += mcur[u];
            score += fm * Tlds[(prevTag << 5) + tcur[u]];
            if (tb + u < Ln - 1) score += fm * gv[u];
            prevTag = tcur[u];
        }
        adj = 0.f;
        tcur[0]=a0.x; tcur[1]=a0.y; tcur[2]=a0.z; tcur[3]=a0.w;
        tcur[4]=a1.x; tcur[5]=a1.y; tcur[6]=a1.z; tcur[7]=a1.w;
        mcur[0]=c0.x; mcur[1]=c0.y; mcur[2]=c0.z; mcur[3]=c0.w;
        mcur[4]=c1.x; mcur[5]=c1.y; mcur[6]=c1.z; mcur[7]=c1.w;
    };

    // ---- prologue: fill emission pipeline
    #pragma unroll
    for (int u = 0; u < 8; ++u) loadEm(t0 + u, buf[u]);

    if (s == 0) {
        loadTagsMask(0);
        initStep(buf[0]);            // t = 0: alpha_0 = e_0
        loadEm(8, buf[0]);
        float g0 = emis[eb + tcur[0]];
        score += (float)mcur[0] * g0;    // emit(t=0)
        msum += mcur[0];
        prevTag = tcur[0];
        float gv[8];
        #pragma unroll
        for (int u = 1; u < 8; ++u) gv[u] = emis[eb + (size_t)u * Cn + tcur[u]];
        #pragma unroll
        for (int u = 1; u < 8; ++u) {    // t = 1..7, scored
            stepMfma(buf[u], 0.f);
            loadEm(u + 8, buf[u]);
            float fm = (float)mcur[u];
            msum += mcur[u];
            score += fm * Tlds[(prevTag << 5) + tcur[u]];
            score += fm * gv[u];
            prevTag = tcur[u];
        }
        loadTagsMask(8);
        renorm();
        #pragma unroll 1
        for (int blk = 0; blk < 15; ++blk) {   // t = 8..127
            realBlock(8 + 8 * blk);
            if (blk < 14) renorm();
        }
    } else {
        initStep(buf[0]);            // warm-up start: alpha := e_{t0}
        loadEm(t0 + 8, buf[0]);
        #pragma unroll
        for (int u = 1; u < 8; ++u) {
            stepMfma(buf[u], 0.f);
            loadEm(t0 + 8 + u, buf[u]);
        }
        renorm();
        prevTag = tags[tB + s * SEGLEN - 1];
        loadTagsMask(s * SEGLEN);
        // warm-up block 2: t0+8 .. t0+15 (= seg start - 1)
        #pragma unroll
        for (int u = 0; u < 8; ++u) {
            stepMfma(buf[u], (u == 0) ? adj : 0.f);
            loadEm(min(t0 + u + 16, Ln - 1), buf[u]);
        }
        adj = 0.f;
        float S = sumD();            // sum-normalize at boundary; Delta counts from here
        adj = -__log2f(S);
        offF = 0.f;
        #pragma unroll 1
        for (int blk = 0; blk < 16; ++blk) {   // t = 128s .. 128s+127
            realBlock(s * SEGLEN + 8 * blk);
            if (blk < 15) renorm();
        }
    }

    float Sf = sumD();
    float delta = offF + __logf(Sf);
    if (lane < 32) {
        dDelta[s * Bn + b] = delta;
        dScore[s * Bn + b] = score;
        dMsum [s * Bn + b] = msum;
    }
}

__global__ void crf_final(const float* __restrict__ dDelta, const float* __restrict__ dScore,
                          const int* __restrict__ dMsum, const int* __restrict__ tags,
                          const float* __restrict__ emis, float* __restrict__ out)
{
    __shared__ float red[8];
    int b = threadIdx.x;   // 512 threads = one per batch
    float lz = 0.f, sc = 0.f; int ms = 0;
    #pragma unroll
    for (int s2 = 0; s2 < NSEG; ++s2) {
        lz += dDelta[s2 * Bn + b];
        sc += dScore[s2 * Bn + b];
        ms += dMsum [s2 * Bn + b];
    }
    int last_idx = max(ms - 1, 0);
    int le_t     = max(ms, 1) - 1;
    int lt = tags[(size_t)b * Ln + last_idx];
    float le = emis[((size_t)b * Ln + le_t) * Cn + lt];
    float val = lz - (sc + le);
    #pragma unroll
    for (int o = 32; o > 0; o >>= 1) val += __shfl_down(val, o, 64);
    if ((b & 63) == 0) red[b >> 6] = val;
    __syncthreads();
    if (b == 0) {
        float t = 0.f;
        #pragma unroll
        for (int w = 0; w < 8; ++w) t += red[w];
        out[0] = t * (1.0f / (float)Bn);
    }
}

extern "C" void kernel_launch(void* const* d_in, const int* in_sizes, int n_in,
                              void* d_out, int out_size, void* d_ws, size_t ws_size,
                              hipStream_t stream)
{
    const float* emis  = (const float*)d_in[0];
    const float* trans = (const float*)d_in[1];
    const int*   tags  = (const int*)d_in[2];
    const int*   mask  = (const int*)d_in[3];
    float* wsf = (float*)d_ws;
    float* dDelta = wsf;                       // 16*512 f32
    float* dScore = wsf + NSEG * Bn;           // 16*512 f32
    int*   dMsum  = (int*)(wsf + 2 * NSEG * Bn); // 16*512 i32
    crf_scan<<<NGRP * NSEG, 64, 0, stream>>>(emis, trans, tags, mask, dDelta, dScore, dMsum);
    crf_final<<<1, Bn, 0, stream>>>(dDelta, dScore, dMsum, tags, emis, (float*)d_out);
}